// Round 1
// baseline (430.246 us; speedup 1.0000x reference)
//
#include <hip/hip_runtime.h>
#include <hip/hip_bf16.h>

// Causal flash attention, B=4 H=16 S=2048 DK=DV=128, fp32 in/out, bf16 MFMA compute.
// Block = 256 threads (4 waves); wave handles 16 q rows; KV tile = 64 keys.

#define S_LEN 2048
#define DKC   128
#define DVC   128
#define BM    64
#define BN    64
#define KPAD  136   // K LDS row stride (bf16): 272B = 17*16 -> b128-aligned, 2-way banks
#define VPAD  72    // Vt LDS row stride:      144B =  9*16 -> b128-aligned, 2-way banks
#define PPAD  72

typedef __bf16 bf16;
typedef bf16  bf16x8 __attribute__((ext_vector_type(8)));
typedef float f32x4  __attribute__((ext_vector_type(4)));

__global__ __launch_bounds__(256, 2)
void fa_kernel(const float* __restrict__ Q, const float* __restrict__ K,
               const float* __restrict__ V, float* __restrict__ O) {
  __shared__ bf16 Klds[BN][KPAD];        // [key][d]
  __shared__ bf16 Vlds[DVC][VPAD];       // transposed: [dv][key]
  __shared__ bf16 Plds[4][16][PPAD];     // per-wave P staging [wave][q][key]

  const int tid  = threadIdx.x;
  const int w    = tid >> 6;
  const int lane = tid & 63;
  const int quad = lane >> 4;
  const int l16  = lane & 15;

  // XCD-aware swizzle: bh pinned to one XCD (lin%8); qtile fast within bh group.
  const int lin  = blockIdx.x;
  const int xcd  = lin & 7;
  const int idx  = lin >> 3;            // 0..255
  const int qtile = 31 - (idx & 31);    // heavy (long-K) tiles first
  const int bh    = xcd + 8 * (idx >> 5);

  const int q0 = qtile * BM;
  const size_t base = (size_t)bh * S_LEN * DKC;
  const float* Qp = Q + base;
  const float* Kp = K + base;
  const float* Vp = V + base;
  float*       Op = O + base;           // DVC==DKC, same stride

  // fold 1/sqrt(128) and log2(e) into Q so softmax runs in base-2
  const float SCALE2 = 0.08838834764831845f * 1.4426950408889634f;

  // ---- Q fragments (A layout: lane holds Q[q=l16][k=quad*8+j], 4 k-chunks) ----
  bf16x8 qf[4];
  {
    const int qg = q0 + w * 16 + l16;
    const float* qrow = Qp + (size_t)qg * DKC;
#pragma unroll
    for (int c = 0; c < 4; ++c) {
      const float* p = qrow + c * 32 + quad * 8;
      float4 x = *(const float4*)p;
      float4 y = *(const float4*)(p + 4);
      bf16x8 f;
      f[0] = (bf16)(x.x * SCALE2); f[1] = (bf16)(x.y * SCALE2);
      f[2] = (bf16)(x.z * SCALE2); f[3] = (bf16)(x.w * SCALE2);
      f[4] = (bf16)(y.x * SCALE2); f[5] = (bf16)(y.y * SCALE2);
      f[6] = (bf16)(y.z * SCALE2); f[7] = (bf16)(y.w * SCALE2);
      qf[c] = f;
    }
  }

  f32x4 oacc[8];
#pragma unroll
  for (int n = 0; n < 8; ++n)
#pragma unroll
    for (int r = 0; r < 4; ++r) oacc[n][r] = 0.0f;
  float mrow[4], lrow[4];
#pragma unroll
  for (int r = 0; r < 4; ++r) { mrow[r] = -1e30f; lrow[r] = 0.0f; }

  const int ntiles = q0 / BN + 1;
  for (int t = 0; t < ntiles; ++t) {
    const int kvb = t * BN;
    __syncthreads();  // all waves done reading previous K/V tile

    // ---- stage K tile (coalesced float4 read, natural layout, b64-ish writes) ----
#pragma unroll
    for (int i = 0; i < 8; ++i) {
      int r  = (tid >> 5) + i * 8;        // 0..63
      int c4 = (tid & 31) * 4;            // 0..124
      float4 kx = *(const float4*)(Kp + (size_t)(kvb + r) * DKC + c4);
      bf16* d = &Klds[r][c4];
      d[0] = (bf16)kx.x; d[1] = (bf16)kx.y; d[2] = (bf16)kx.z; d[3] = (bf16)kx.w;
    }
    // ---- stage V transposed: k varies fast across lanes -> conflict-free scatter ----
#pragma unroll
    for (int i = 0; i < 8; ++i) {
      int k  = (tid & 31) + 32 * (i & 1);            // 0..63
      int d4 = ((tid >> 5) + 8 * (i >> 1)) * 4;      // 0..124
      float4 vx = *(const float4*)(Vp + (size_t)(kvb + k) * DVC + d4);
      Vlds[d4 + 0][k] = (bf16)vx.x;
      Vlds[d4 + 1][k] = (bf16)vx.y;
      Vlds[d4 + 2][k] = (bf16)vx.z;
      Vlds[d4 + 3][k] = (bf16)vx.w;
    }
    __syncthreads();

    // ---- S = Q K^T (16 q rows x 64 keys), fp32 accum ----
    f32x4 sacc[4];
#pragma unroll
    for (int n = 0; n < 4; ++n)
#pragma unroll
      for (int r = 0; r < 4; ++r) sacc[n][r] = 0.0f;
#pragma unroll
    for (int c = 0; c < 4; ++c) {
#pragma unroll
      for (int n = 0; n < 4; ++n) {
        bf16x8 kf = *(const bf16x8*)&Klds[n * 16 + l16][c * 32 + quad * 8];
        sacc[n] = __builtin_amdgcn_mfma_f32_16x16x32_bf16(qf[c], kf, sacc[n], 0, 0, 0);
      }
    }

    // ---- causal mask (diagonal tile only; key kvb is always unmasked) ----
    if (t == ntiles - 1) {
#pragma unroll
      for (int n = 0; n < 4; ++n) {
        int kg = kvb + n * 16 + l16;
#pragma unroll
        for (int r = 0; r < 4; ++r) {
          int qg = q0 + w * 16 + quad * 4 + r;
          if (kg > qg) sacc[n][r] = -1e30f;
        }
      }
    }

    // ---- online softmax (base-2): rowmax over quad's 16 lanes ----
    float pex[4][4];
#pragma unroll
    for (int r = 0; r < 4; ++r) {
      float mx = fmaxf(fmaxf(sacc[0][r], sacc[1][r]), fmaxf(sacc[2][r], sacc[3][r]));
      mx = fmaxf(mx, __shfl_xor(mx, 1));
      mx = fmaxf(mx, __shfl_xor(mx, 2));
      mx = fmaxf(mx, __shfl_xor(mx, 4));
      mx = fmaxf(mx, __shfl_xor(mx, 8));
      float mnew  = fmaxf(mrow[r], mx);
      float alpha = exp2f(mrow[r] - mnew);
      mrow[r] = mnew;
      float ps = 0.0f;
#pragma unroll
      for (int n = 0; n < 4; ++n) {
        float p = exp2f(sacc[n][r] - mnew);
        pex[n][r] = p;
        ps += p;
      }
      lrow[r] = lrow[r] * alpha + ps;   // per-lane partial; reduced in epilogue
#pragma unroll
      for (int n = 0; n < 8; ++n) oacc[n][r] *= alpha;
    }

    // ---- P: C-layout -> LDS -> A-layout ----
#pragma unroll
    for (int n = 0; n < 4; ++n)
#pragma unroll
      for (int r = 0; r < 4; ++r)
        Plds[w][quad * 4 + r][n * 16 + l16] = (bf16)pex[n][r];
    __syncthreads();

    // ---- O += P V ----
#pragma unroll
    for (int c = 0; c < 2; ++c) {
      bf16x8 pf = *(const bf16x8*)&Plds[w][l16][c * 32 + quad * 8];
#pragma unroll
      for (int n = 0; n < 8; ++n) {
        bf16x8 vf = *(const bf16x8*)&Vlds[n * 16 + l16][c * 32 + quad * 8];
        oacc[n] = __builtin_amdgcn_mfma_f32_16x16x32_bf16(pf, vf, oacc[n], 0, 0, 0);
      }
    }
  }

  // ---- epilogue: reduce l across quad lanes, normalize, store ----
  float linv[4];
#pragma unroll
  for (int r = 0; r < 4; ++r) {
    float s = lrow[r];
    s += __shfl_xor(s, 1);
    s += __shfl_xor(s, 2);
    s += __shfl_xor(s, 4);
    s += __shfl_xor(s, 8);
    linv[r] = 1.0f / s;
  }
#pragma unroll
  for (int n = 0; n < 8; ++n) {
#pragma unroll
    for (int r = 0; r < 4; ++r) {
      int qg = q0 + w * 16 + quad * 4 + r;
      Op[(size_t)qg * DVC + n * 16 + l16] = oacc[n][r] * linv[r];
    }
  }
}

extern "C" void kernel_launch(void* const* d_in, const int* in_sizes, int n_in,
                              void* d_out, int out_size, void* d_ws, size_t ws_size,
                              hipStream_t stream) {
  const float* Q = (const float*)d_in[0];
  const float* K = (const float*)d_in[1];
  const float* V = (const float*)d_in[2];
  // d_in[3] is the causal tril mask; causality is applied analytically.
  float* O = (float*)d_out;
  dim3 grid(2048);   // 64 bh * 32 q-tiles, XCD-swizzled in-kernel
  fa_kernel<<<grid, 256, 0, stream>>>(Q, K, V, O);
}